// Round 4
// baseline (673.909 us; speedup 1.0000x reference)
//
#include <hip/hip_runtime.h>
#include <hip/hip_bf16.h>

typedef __hip_bfloat16 bf16;

#define BNS 0.9995003746877732f  // 1/sqrt(1+1e-3)

__device__ __forceinline__ float lrelu(float x) { return x > 0.f ? x : 0.2f * x; }

struct b4 { bf16 a, b, c, d; };  // 8-byte bf16 quad

__device__ __forceinline__ float4 load4(const float* p) {
    return *reinterpret_cast<const float4*>(p);
}
__device__ __forceinline__ float4 load4(const bf16* p) {
    const b4 q = *reinterpret_cast<const b4*>(p);
    return make_float4(__bfloat162float(q.a), __bfloat162float(q.b),
                       __bfloat162float(q.c), __bfloat162float(q.d));
}
__device__ __forceinline__ void store1(float* p, float v) { *p = v; }
__device__ __forceinline__ void store1(bf16* p, float v) { *p = __float2bfloat16(v); }

// ---------------------------------------------------------------------------
// Stage 0: concat(fixed,moving) -> conv3x3 (2->32) SAME -> BN*lrelu -> avgpool2
// in: fixed/moving [4,512,512,1] f32   out a0: [4,256,256,32] bf16
// ---------------------------------------------------------------------------
__global__ __launch_bounds__(256) void k_stage0(const float* __restrict__ fx,
                                                const float* __restrict__ mv,
                                                const float* __restrict__ w0,
                                                bf16* __restrict__ out)
{
    __shared__ float ws[576];  // [ky][kx][ci][co]
    const int tid = threadIdx.y * 32 + threadIdx.x;
    for (int i = tid; i < 576; i += 256) ws[i] = w0[i];
    __syncthreads();

    const int co = threadIdx.x;
    const int px = blockIdx.x * 8 + threadIdx.y;
    const int py = blockIdx.y;
    const int b  = blockIdx.z;

    float vf[4][4], vm[4][4];
#pragma unroll
    for (int r = 0; r < 4; ++r) {
        const int iy  = 2 * py - 1 + r;
        const bool oky = (unsigned)iy < 512u;
        const int iyc = oky ? iy : 0;
#pragma unroll
        for (int c = 0; c < 4; ++c) {
            const int ix  = 2 * px - 1 + c;
            const bool ok = oky && ((unsigned)ix < 512u);
            const int ixc = ok ? ix : 0;
            const size_t idx = ((size_t)b * 512 + iyc) * 512 + ixc;
            vf[r][c] = ok ? fx[idx] : 0.f;
            vm[r][c] = ok ? mv[idx] : 0.f;
        }
    }

    float acc[2][2] = {{0.f, 0.f}, {0.f, 0.f}};
#pragma unroll
    for (int ky = 0; ky < 3; ++ky)
#pragma unroll
        for (int kx = 0; kx < 3; ++kx) {
            const float wfv = ws[((ky * 3 + kx) * 2 + 0) * 32 + co];
            const float wmv = ws[((ky * 3 + kx) * 2 + 1) * 32 + co];
#pragma unroll
            for (int dy = 0; dy < 2; ++dy)
#pragma unroll
                for (int dx = 0; dx < 2; ++dx)
                    acc[dy][dx] += vf[dy + ky][dx + kx] * wfv + vm[dy + ky][dx + kx] * wmv;
        }

    const float r = 0.25f * (lrelu(BNS * acc[0][0]) + lrelu(BNS * acc[0][1]) +
                             lrelu(BNS * acc[1][0]) + lrelu(BNS * acc[1][1]));
    out[(((size_t)b * 256 + py) * 256 + px) * 32 + co] = __float2bfloat16(r);
}

// ---------------------------------------------------------------------------
// conv3x3 (32->32) SAME -> BN*lrelu -> avgpool2.  Templated in/out dtype.
// LDS weights as [k][cig][co][4] float4 per-lane.
// ---------------------------------------------------------------------------
template <typename Tin, typename Tout>
__global__ __launch_bounds__(256) void k_conv_pool(const Tin* __restrict__ in,
                                                   const float* __restrict__ wg,
                                                   Tout* __restrict__ out,
                                                   int Hi, int Wi)
{
    __shared__ float wl[9216];  // [k][cig][co][j]
    const int tid = threadIdx.y * 32 + threadIdx.x;
    for (int i = tid; i < 9216; i += 256) {
        const int k = i >> 10, r = i & 1023;
        const int ci = r >> 5, co = r & 31;
        wl[((k * 8 + (ci >> 2)) * 32 + co) * 4 + (ci & 3)] = wg[i];
    }
    __syncthreads();

    const int co = threadIdx.x;
    const int px = blockIdx.x * 8 + threadIdx.y;
    const int py = blockIdx.y;
    const int b  = blockIdx.z;
    const int Ho = Hi >> 1, Wo = Wi >> 1;

    float acc[2][2] = {{0.f, 0.f}, {0.f, 0.f}};
#pragma unroll
    for (int ky = 0; ky < 3; ++ky) {
#pragma unroll
        for (int kx = 0; kx < 3; ++kx) {
            const int k = ky * 3 + kx;
#pragma unroll
            for (int g = 0; g < 8; ++g) {
                const float4 wv = *reinterpret_cast<const float4*>(&wl[((k * 8 + g) * 32 + co) * 4]);
#pragma unroll
                for (int dy = 0; dy < 2; ++dy) {
                    const int iy = 2 * py + dy + ky - 1;
                    if ((unsigned)iy >= (unsigned)Hi) continue;
#pragma unroll
                    for (int dx = 0; dx < 2; ++dx) {
                        const int ix = 2 * px + dx + kx - 1;
                        if ((unsigned)ix >= (unsigned)Wi) continue;
                        const float4 iv = load4(&in[(((size_t)b * Hi + iy) * Wi + ix) * 32 + g * 4]);
                        acc[dy][dx] += iv.x * wv.x + iv.y * wv.y + iv.z * wv.z + iv.w * wv.w;
                    }
                }
            }
        }
    }
    const float r = 0.25f * (lrelu(BNS * acc[0][0]) + lrelu(BNS * acc[0][1]) +
                             lrelu(BNS * acc[1][0]) + lrelu(BNS * acc[1][1]));
    store1(&out[(((size_t)b * Ho + py) * Wo + px) * 32 + co], r);
}

// ---------------------------------------------------------------------------
// conv3x3 (32->32) SAME -> BN*lrelu (no pool), 64x64 f32. Two rows/thread.
// ---------------------------------------------------------------------------
__global__ __launch_bounds__(256) void k_conv_fw(const float* __restrict__ in,
                                                 const float* __restrict__ wg,
                                                 float* __restrict__ out)
{
    __shared__ float wl[9216];
    const int tid = threadIdx.y * 32 + threadIdx.x;
    for (int i = tid; i < 9216; i += 256) {
        const int k = i >> 10, r = i & 1023;
        const int ci = r >> 5, co = r & 31;
        wl[((k * 8 + (ci >> 2)) * 32 + co) * 4 + (ci & 3)] = wg[i];
    }
    __syncthreads();

    const int co = threadIdx.x;
    const int x  = blockIdx.x * 8 + threadIdx.y;
    const int y0 = blockIdx.y * 2;
    const int b  = blockIdx.z;

    float acc[2] = {0.f, 0.f};
#pragma unroll
    for (int ky = 0; ky < 3; ++ky) {
#pragma unroll
        for (int kx = 0; kx < 3; ++kx) {
            const int k  = ky * 3 + kx;
            const int ix = x + kx - 1;
            const bool okx = (unsigned)ix < 64u;
#pragma unroll
            for (int g = 0; g < 8; ++g) {
                const float4 wv = *reinterpret_cast<const float4*>(&wl[((k * 8 + g) * 32 + co) * 4]);
#pragma unroll
                for (int r = 0; r < 2; ++r) {
                    const int iy = y0 + r + ky - 1;
                    if (okx && (unsigned)iy < 64u) {
                        const float4 iv = load4(&in[(((size_t)b * 64 + iy) * 64 + ix) * 32 + g * 4]);
                        acc[r] += iv.x * wv.x + iv.y * wv.y + iv.z * wv.z + iv.w * wv.w;
                    }
                }
            }
        }
    }
#pragma unroll
    for (int r = 0; r < 2; ++r)
        out[(((size_t)b * 64 + (y0 + r)) * 64 + x) * 32 + co] = lrelu(BNS * acc[r]);
}

// ---------------------------------------------------------------------------
// Fused pw0 (1x1 32->32, lrelu, NO BN) + pw1 (1x1 32->2) -> disp [4,64,64,2] f32
// ---------------------------------------------------------------------------
__global__ __launch_bounds__(256) void k_pw(const float* __restrict__ in,
                                            const float* __restrict__ pw0,
                                            const float* __restrict__ pw1,
                                            float* __restrict__ disp)
{
    __shared__ float w0t[1024];  // [co][ci]
    __shared__ float w1s[64];    // [co][c]
    const int tid = threadIdx.x;
    for (int i = tid; i < 1024; i += 256) {
        const int ci = i >> 5, co = i & 31;
        w0t[co * 32 + ci] = pw0[i];
    }
    if (tid < 64) w1s[tid] = pw1[tid];
    __syncthreads();

    const int p = blockIdx.x * 256 + tid;  // 16384 pixels
    float4 iv[8];
#pragma unroll
    for (int g = 0; g < 8; ++g)
        iv[g] = *reinterpret_cast<const float4*>(&in[(size_t)p * 32 + g * 4]);

    float d0 = 0.f, d1 = 0.f;
#pragma unroll 4
    for (int co = 0; co < 32; ++co) {
        float s = 0.f;
#pragma unroll
        for (int g = 0; g < 8; ++g) {
            const float4 wv = *reinterpret_cast<const float4*>(&w0t[co * 32 + g * 4]);
            s += iv[g].x * wv.x + iv[g].y * wv.y + iv[g].z * wv.z + iv[g].w * wv.w;
        }
        const float p0 = lrelu(s);  // pw0 has NO BN scale
        d0 += p0 * w1s[co * 2 + 0];
        d1 += p0 * w1s[co * 2 + 1];
    }
    disp[(size_t)p * 2 + 0] = d0;
    disp[(size_t)p * 2 + 1] = d1;
}

// ---------------------------------------------------------------------------
// B-spline upsample + bilinear warp + pack outputs. Flat 1D over B*H*W.
// Degenerate clip cases (x0i==x1i or y0i==y1i) produce EXACTLY 0 in the
// reference's arithmetic -> explicit branch.
// out (FLOAT32): [warped 4*512*512 | warped_grid 4*2*512*512]
// ---------------------------------------------------------------------------
__global__ __launch_bounds__(256) void k_warp(const float* __restrict__ disp,
                                              const float* __restrict__ mv,
                                              float* __restrict__ out)
{
    const int idx = blockIdx.x * 256 + threadIdx.x;  // [0, 1048576)
    const int b = idx >> 18;
    const int h = (idx >> 9) & 511;
    const int w = idx & 511;

    const float xg = fminf(w * 0.125f, 63.0f);
    const float yg = fminf(h * 0.125f, 63.0f);
    const int ii = w >> 3, jj = h >> 3;
    const float u = xg * 0.015625f, v = yg * 0.015625f;  // /64

    const float u2 = u * u, u3 = u2 * u;
    const float v2 = v * v, v3 = v2 * v;
    const float Bu[4] = {-u3 + 3.f * u2 - 3.f * u + 1.f,
                         3.f * u3 - 6.f * u2 + 4.f,
                         -3.f * u3 + 3.f * u2 + 3.f * u + 1.f,
                         u3};
    const float Bv[4] = {-v3 + 3.f * v2 - 3.f * v + 1.f,
                         3.f * v3 - 6.f * v2 + 4.f,
                         -3.f * v3 + 3.f * v2 + 3.f * v + 1.f,
                         v3};

    float s0 = 0.f, s1 = 0.f;
#pragma unroll
    for (int m = 0; m < 4; ++m) {
        const int gy = jj + m - 1;
        float r0 = 0.f, r1 = 0.f;
        if ((unsigned)gy < 64u) {
#pragma unroll
            for (int n = 0; n < 4; ++n) {
                const int gx = ii + n - 1;
                if ((unsigned)gx < 64u) {
                    const size_t di = (((size_t)b * 64 + gy) * 64 + gx) * 2;
                    r0 += Bv[n] * disp[di];
                    r1 += Bv[n] * disp[di + 1];
                }
            }
        }
        s0 += Bu[m] * r0;  // B_u pairs with the row-offset axis, per reference
        s1 += Bu[m] * r1;
    }
    const float wx = s0 + (float)w;
    const float wy = s1 + (float)h;

    // bilinear sample of moving[..,0]
    const float fx = floorf(wx), fy = floorf(wy);
    const float x0 = fminf(fmaxf(fx, 0.f), 511.f);
    const float x1 = fminf(fmaxf(fx + 1.f, 0.f), 511.f);
    const float y0 = fminf(fmaxf(fy, 0.f), 511.f);
    const float y1 = fminf(fmaxf(fy + 1.f, 0.f), 511.f);
    const int x0i = (int)x0, x1i = (int)x1, y0i = (int)y0, y1i = (int)y1;

    float ov;
    if (x0i == x1i || y0i == y1i) {
        ov = 0.f;  // exact result of the reference's cancelling arithmetic
    } else {
        const size_t bb = (size_t)b * 262144;
        const float Q1 = mv[bb + (size_t)y0i * 512 + x0i];
        const float Q2 = mv[bb + (size_t)y1i * 512 + x0i];
        const float Q3 = mv[bb + (size_t)y0i * 512 + x1i];
        const float Q4 = mv[bb + (size_t)y1i * 512 + x1i];
        const float invdx = 1.f / (x1 - x0 + 1e-5f);
        const float wxr = (x1 - wx) * invdx, wxl = (wx - x0) * invdx;
        const float R1 = wxr * Q1 + wxl * Q3;
        const float R2 = wxr * Q2 + wxl * Q4;
        const float invdy = 1.f / (y1 - y0 + 1e-5f);
        ov = (y1 - wy) * invdy * R1 + (wy - y0) * invdy * R2;
    }

    out[idx] = ov;                                          // warped [B,H,W,1] flat
    const size_t gbase = 1048576;                           // grid region start
    out[gbase + (size_t)(b * 2 + 0) * 262144 + (size_t)h * 512 + w] = wx;
    out[gbase + (size_t)(b * 2 + 1) * 262144 + (size_t)h * 512 + w] = wy;
}

// ---------------------------------------------------------------------------
extern "C" void kernel_launch(void* const* d_in, const int* in_sizes, int n_in,
                              void* d_out, int out_size, void* d_ws, size_t ws_size,
                              hipStream_t stream) {
    (void)in_sizes; (void)n_in; (void)out_size; (void)ws_size;
    const float* fixed  = (const float*)d_in[0];
    const float* moving = (const float*)d_in[1];
    const float* w0  = (const float*)d_in[2];
    const float* w1  = (const float*)d_in[3];
    const float* w2  = (const float*)d_in[4];
    const float* fw0 = (const float*)d_in[5];
    const float* fw1 = (const float*)d_in[6];
    const float* pw0 = (const float*)d_in[7];
    const float* pw1 = (const float*)d_in[8];

    // Workspace plan (peak 20.1 MB):
    //   a0  bf16 [4,256,256,32] @ [0,16MB)      live k0..k1
    //   a1  bf16 [4,128,128,32] @ [16MB,20MB)   live k1..k2
    //   a2  f32  [4,64,64,32]   @ [0,2MB)       (reuses a0; a0 dead at k2)
    //   f0  f32  [4,64,64,32]   @ [2MB,4MB)
    //   f1  f32  [4,64,64,32]   @ [4MB,6MB)
    //   dsp f32  [4,64,64,2]    @ [6MB,6.125MB)
    char* base = (char*)d_ws;
    bf16*  a0  = (bf16*)base;
    bf16*  a1  = (bf16*)(base + (16u << 20));
    float* a2  = (float*)base;
    float* f0  = (float*)(base + (2u << 20));
    float* f1  = (float*)(base + (4u << 20));
    float* dsp = (float*)(base + (6u << 20));

    k_stage0<<<dim3(32, 256, 4), dim3(32, 8), 0, stream>>>(fixed, moving, w0, a0);
    k_conv_pool<bf16, bf16><<<dim3(16, 128, 4), dim3(32, 8), 0, stream>>>(a0, w1, a1, 256, 256);
    k_conv_pool<bf16, float><<<dim3(8, 64, 4), dim3(32, 8), 0, stream>>>(a1, w2, a2, 128, 128);
    k_conv_fw<<<dim3(8, 32, 4), dim3(32, 8), 0, stream>>>(a2, fw0, f0);
    k_conv_fw<<<dim3(8, 32, 4), dim3(32, 8), 0, stream>>>(f0, fw1, f1);
    k_pw<<<64, 256, 0, stream>>>(f1, pw0, pw1, dsp);
    k_warp<<<4096, 256, 0, stream>>>(dsp, moving, (float*)d_out);
}

// Round 5
// 178.827 us; speedup vs baseline: 3.7685x; 3.7685x over previous
//
#include <hip/hip_runtime.h>
#include <hip/hip_bf16.h>

typedef __hip_bfloat16 bf16;
typedef __attribute__((ext_vector_type(8))) short s8v;     // 8 bf16 = 4 VGPRs
typedef __attribute__((ext_vector_type(16))) float f16v;   // MFMA 32x32 accumulator

#define BNS 0.9995003746877732f  // 1/sqrt(1+1e-3)

__device__ __forceinline__ float lrelu(float x) { return x > 0.f ? x : 0.2f * x; }

struct b4 { bf16 a, b, c, d; };
__device__ __forceinline__ float4 load4(const bf16* p) {
    const b4 q = *reinterpret_cast<const b4*>(p);
    return make_float4(__bfloat162float(q.a), __bfloat162float(q.b),
                       __bfloat162float(q.c), __bfloat162float(q.d));
}

// ---------------------------------------------------------------------------
// Weight repack: f32 [3,3,32,32] -> bf16 B-fragment order Wf[t][lane][j]
//   k = t*16 + (lane>>5)*8 + j ; tap = k>>5 ; ci = k&31 ; co = lane&31
// 4 layers x 9216 elements. Output lives in d_out (overwritten by k_warp later).
// ---------------------------------------------------------------------------
__global__ __launch_bounds__(256) void k_repack(const float* __restrict__ wa,
                                                const float* __restrict__ wb,
                                                const float* __restrict__ wc,
                                                const float* __restrict__ wd,
                                                bf16* __restrict__ wf)
{
    const int idx = blockIdx.x * 256 + threadIdx.x;   // [0, 36864)
    const int layer = idx / 9216;
    const int r = idx - layer * 9216;
    const int j = r & 7;
    const int l = (r >> 3) & 63;
    const int t = r >> 9;                              // [0,18)
    const int k = t * 16 + ((l >> 5) << 3) + j;
    const int tap = k >> 5, ci = k & 31, co = l & 31;
    const float* W = layer == 0 ? wa : layer == 1 ? wb : layer == 2 ? wc : wd;
    wf[idx] = __float2bfloat16(W[(tap * 32 + ci) * 32 + co]);
}

// ---------------------------------------------------------------------------
// Stage 0: concat(fixed,moving) -> conv3x3 (2->32) SAME -> BN*lrelu -> avgpool2
// in: fixed/moving [4,512,512,1] f32   out a0: [4,256,256,32] bf16
// ---------------------------------------------------------------------------
__global__ __launch_bounds__(256) void k_stage0(const float* __restrict__ fx,
                                                const float* __restrict__ mv,
                                                const float* __restrict__ w0,
                                                bf16* __restrict__ out)
{
    __shared__ float ws[576];  // [ky][kx][ci][co]
    const int tid = threadIdx.y * 32 + threadIdx.x;
    for (int i = tid; i < 576; i += 256) ws[i] = w0[i];
    __syncthreads();

    const int co = threadIdx.x;
    const int px = blockIdx.x * 8 + threadIdx.y;
    const int py = blockIdx.y;
    const int b  = blockIdx.z;

    float vf[4][4], vm[4][4];
#pragma unroll
    for (int r = 0; r < 4; ++r) {
        const int iy  = 2 * py - 1 + r;
        const bool oky = (unsigned)iy < 512u;
        const int iyc = oky ? iy : 0;
#pragma unroll
        for (int c = 0; c < 4; ++c) {
            const int ix  = 2 * px - 1 + c;
            const bool ok = oky && ((unsigned)ix < 512u);
            const int ixc = ok ? ix : 0;
            const size_t idx = ((size_t)b * 512 + iyc) * 512 + ixc;
            vf[r][c] = ok ? fx[idx] : 0.f;
            vm[r][c] = ok ? mv[idx] : 0.f;
        }
    }

    float acc[2][2] = {{0.f, 0.f}, {0.f, 0.f}};
#pragma unroll
    for (int ky = 0; ky < 3; ++ky)
#pragma unroll
        for (int kx = 0; kx < 3; ++kx) {
            const float wfv = ws[((ky * 3 + kx) * 2 + 0) * 32 + co];
            const float wmv = ws[((ky * 3 + kx) * 2 + 1) * 32 + co];
#pragma unroll
            for (int dy = 0; dy < 2; ++dy)
#pragma unroll
                for (int dx = 0; dx < 2; ++dx)
                    acc[dy][dx] += vf[dy + ky][dx + kx] * wfv + vm[dy + ky][dx + kx] * wmv;
        }

    const float r = 0.25f * (lrelu(BNS * acc[0][0]) + lrelu(BNS * acc[0][1]) +
                             lrelu(BNS * acc[1][0]) + lrelu(BNS * acc[1][1]));
    out[(((size_t)b * 256 + py) * 256 + px) * 32 + co] = __float2bfloat16(r);
}

// ---------------------------------------------------------------------------
// MFMA implicit-GEMM conv3x3 (32->32) SAME -> BN*lrelu [-> avgpool2]
// GEMM: M = pre-pool pixels, N = 32 co, K = 288 (9 taps x 32 ci), 18 MFMA steps.
// Block = 4 waves; wave = 2 rows x 16 cols pre-pool tile; block tile = 8x16.
// A from LDS (pixel stride 40 shorts: 16B-aligned b128, 2-way banks = free).
// B frags straight from global (coalesced dwordx4, L1-hot, identical all waves).
// Pool is fully in-register thanks to the 32x32 C/D row mapping.
// ---------------------------------------------------------------------------
template <bool POOL>
__global__ __launch_bounds__(256) void k_conv_mfma(const bf16* __restrict__ in,
                                                   const bf16* __restrict__ wf,
                                                   bf16* __restrict__ out,
                                                   int Hi, int Wi)
{
    __shared__ __align__(16) short lds[7200];  // 180 pixels x 40 shorts (32 ci + pad)
    const int tid  = threadIdx.x;
    const int lane = tid & 63;
    const int wv   = tid >> 6;
    const int x0 = blockIdx.x * 16;
    const int y0 = blockIdx.y * 8;
    const int b  = blockIdx.z;

    // stage [y0-1 .. y0+8] x [x0-1 .. x0+16] x 32ci, zero-padded borders
    for (int i = tid; i < 1440; i += 256) {
        const int c4 = i & 7;
        const int p  = i >> 3;           // [0,180)
        const int row = p / 18, col = p - row * 18;
        const int gy = y0 - 1 + row, gx = x0 - 1 + col;
        uint2 v = make_uint2(0u, 0u);
        if ((unsigned)gy < (unsigned)Hi && (unsigned)gx < (unsigned)Wi)
            v = *reinterpret_cast<const uint2*>(&in[(((size_t)b * Hi + gy) * Wi + gx) * 32 + c4 * 4]);
        *reinterpret_cast<uint2*>(&lds[p * 40 + c4 * 4]) = v;
    }
    __syncthreads();

    const int m  = lane & 31;   // GEMM row = pixel: m = dy*16 + x
    const int h  = lane >> 5;
    const int dy = m >> 4;
    const int xx = m & 15;
    const int rbase = 2 * wv + dy;

    f16v acc;
#pragma unroll
    for (int i = 0; i < 16; ++i) acc[i] = 0.f;

#pragma unroll
    for (int t = 0; t < 18; ++t) {
        const int tap = t >> 1;
        const int ky = tap / 3, kx = tap % 3;
        const int ci_ofs = ((t & 1) << 4) + (h << 3);
        const s8v a = *reinterpret_cast<const s8v*>(
            &lds[((rbase + ky) * 18 + (xx + kx)) * 40 + ci_ofs]);
        const s8v bf = *reinterpret_cast<const s8v*>(&wf[(t * 64 + lane) * 8]);
        acc = __builtin_amdgcn_mfma_f32_32x32x16_bf16(a, bf, acc, 0, 0, 0);
    }

    const int co = lane & 31;
    if (POOL) {
        // lane holds all 4 pool partners of 4 cells: regs {b,b+1,b+8,b+9}
        const int Ho = Hi >> 1, Wo = Wi >> 1;
        const int prow = blockIdx.y * 4 + wv;
#pragma unroll
        for (int q = 0; q < 4; ++q) {
            const int base = ((q & 1) << 1) + ((q >> 1) << 2);
            const float s = lrelu(BNS * acc[base])     + lrelu(BNS * acc[base + 1])
                          + lrelu(BNS * acc[base + 8]) + lrelu(BNS * acc[base + 9]);
            const int c = (q & 1) + 2 * h + ((q >> 1) << 2);   // pooled col within tile
            out[(((size_t)b * Ho + prow) * Wo + (blockIdx.x * 8 + c)) * 32 + co] =
                __float2bfloat16(0.25f * s);
        }
    } else {
#pragma unroll
        for (int r = 0; r < 16; ++r) {
            const int mm = (r & 3) + ((r >> 2) << 3) + (h << 2);
            const int gy = y0 + 2 * wv + (mm >> 4);
            const int gx = x0 + (mm & 15);
            out[(((size_t)b * Hi + gy) * Wi + gx) * 32 + co] =
                __float2bfloat16(lrelu(BNS * acc[r]));
        }
    }
}

// ---------------------------------------------------------------------------
// Fused pw0 (1x1 32->32, lrelu, NO BN) + pw1 (1x1 32->2) -> disp [4,64,64,2] f32
// ---------------------------------------------------------------------------
__global__ __launch_bounds__(256) void k_pw(const bf16* __restrict__ in,
                                            const float* __restrict__ pw0,
                                            const float* __restrict__ pw1,
                                            float* __restrict__ disp)
{
    __shared__ float w0t[1024];  // [co][ci]
    __shared__ float w1s[64];    // [co][c]
    const int tid = threadIdx.x;
    for (int i = tid; i < 1024; i += 256) {
        const int ci = i >> 5, co = i & 31;
        w0t[co * 32 + ci] = pw0[i];
    }
    if (tid < 64) w1s[tid] = pw1[tid];
    __syncthreads();

    const int p = blockIdx.x * 256 + tid;  // 16384 pixels
    float4 iv[8];
#pragma unroll
    for (int g = 0; g < 8; ++g)
        iv[g] = load4(&in[(size_t)p * 32 + g * 4]);

    float d0 = 0.f, d1 = 0.f;
#pragma unroll 4
    for (int co = 0; co < 32; ++co) {
        float s = 0.f;
#pragma unroll
        for (int g = 0; g < 8; ++g) {
            const float4 wv = *reinterpret_cast<const float4*>(&w0t[co * 32 + g * 4]);
            s += iv[g].x * wv.x + iv[g].y * wv.y + iv[g].z * wv.z + iv[g].w * wv.w;
        }
        const float p0 = lrelu(s);  // pw0 has NO BN scale
        d0 += p0 * w1s[co * 2 + 0];
        d1 += p0 * w1s[co * 2 + 1];
    }
    disp[(size_t)p * 2 + 0] = d0;
    disp[(size_t)p * 2 + 1] = d1;
}

// ---------------------------------------------------------------------------
// B-spline upsample + bilinear warp + pack outputs (f32 d_out).
// Degenerate clip cases produce exactly 0 (reference-cancelling arithmetic).
// ---------------------------------------------------------------------------
__global__ __launch_bounds__(256) void k_warp(const float* __restrict__ disp,
                                              const float* __restrict__ mv,
                                              float* __restrict__ out)
{
    const int idx = blockIdx.x * 256 + threadIdx.x;  // [0, 1048576)
    const int b = idx >> 18;
    const int h = (idx >> 9) & 511;
    const int w = idx & 511;

    const float xg = fminf(w * 0.125f, 63.0f);
    const float yg = fminf(h * 0.125f, 63.0f);
    const int ii = w >> 3, jj = h >> 3;
    const float u = xg * 0.015625f, v = yg * 0.015625f;

    const float u2 = u * u, u3 = u2 * u;
    const float v2 = v * v, v3 = v2 * v;
    const float Bu[4] = {-u3 + 3.f * u2 - 3.f * u + 1.f,
                         3.f * u3 - 6.f * u2 + 4.f,
                         -3.f * u3 + 3.f * u2 + 3.f * u + 1.f,
                         u3};
    const float Bv[4] = {-v3 + 3.f * v2 - 3.f * v + 1.f,
                         3.f * v3 - 6.f * v2 + 4.f,
                         -3.f * v3 + 3.f * v2 + 3.f * v + 1.f,
                         v3};

    float s0 = 0.f, s1 = 0.f;
#pragma unroll
    for (int m = 0; m < 4; ++m) {
        const int gy = jj + m - 1;
        float r0 = 0.f, r1 = 0.f;
        if ((unsigned)gy < 64u) {
#pragma unroll
            for (int n = 0; n < 4; ++n) {
                const int gx = ii + n - 1;
                if ((unsigned)gx < 64u) {
                    const size_t di = (((size_t)b * 64 + gy) * 64 + gx) * 2;
                    r0 += Bv[n] * disp[di];
                    r1 += Bv[n] * disp[di + 1];
                }
            }
        }
        s0 += Bu[m] * r0;  // B_u pairs with the row-offset axis, per reference
        s1 += Bu[m] * r1;
    }
    const float wx = s0 + (float)w;
    const float wy = s1 + (float)h;

    const float fx = floorf(wx), fy = floorf(wy);
    const float x0 = fminf(fmaxf(fx, 0.f), 511.f);
    const float x1 = fminf(fmaxf(fx + 1.f, 0.f), 511.f);
    const float y0 = fminf(fmaxf(fy, 0.f), 511.f);
    const float y1 = fminf(fmaxf(fy + 1.f, 0.f), 511.f);
    const int x0i = (int)x0, x1i = (int)x1, y0i = (int)y0, y1i = (int)y1;

    float ov;
    if (x0i == x1i || y0i == y1i) {
        ov = 0.f;
    } else {
        const size_t bb = (size_t)b * 262144;
        const float Q1 = mv[bb + (size_t)y0i * 512 + x0i];
        const float Q2 = mv[bb + (size_t)y1i * 512 + x0i];
        const float Q3 = mv[bb + (size_t)y0i * 512 + x1i];
        const float Q4 = mv[bb + (size_t)y1i * 512 + x1i];
        const float invdx = 1.f / (x1 - x0 + 1e-5f);
        const float wxr = (x1 - wx) * invdx, wxl = (wx - x0) * invdx;
        const float R1 = wxr * Q1 + wxl * Q3;
        const float R2 = wxr * Q2 + wxl * Q4;
        const float invdy = 1.f / (y1 - y0 + 1e-5f);
        ov = (y1 - wy) * invdy * R1 + (wy - y0) * invdy * R2;
    }

    out[idx] = ov;                                          // warped [B,H,W,1]
    const size_t gbase = 1048576;                           // grid region
    out[gbase + (size_t)(b * 2 + 0) * 262144 + (size_t)h * 512 + w] = wx;
    out[gbase + (size_t)(b * 2 + 1) * 262144 + (size_t)h * 512 + w] = wy;
}

// ---------------------------------------------------------------------------
extern "C" void kernel_launch(void* const* d_in, const int* in_sizes, int n_in,
                              void* d_out, int out_size, void* d_ws, size_t ws_size,
                              hipStream_t stream) {
    (void)in_sizes; (void)n_in; (void)out_size; (void)ws_size;
    const float* fixed  = (const float*)d_in[0];
    const float* moving = (const float*)d_in[1];
    const float* w0  = (const float*)d_in[2];
    const float* w1  = (const float*)d_in[3];
    const float* w2  = (const float*)d_in[4];
    const float* fw0 = (const float*)d_in[5];
    const float* fw1 = (const float*)d_in[6];
    const float* pw0 = (const float*)d_in[7];
    const float* pw1 = (const float*)d_in[8];

    // d_ws (max 20 MiB, proven safe in round 4):
    //   a0 bf16 [4,256,256,32] @ [0,16M)    a1 bf16 [4,128,128,32] @ [16M,20M)
    //   a2 bf16 @ [0,1M) (a0 dead)  f0 @ [1M,2M)  f1 @ [2M,3M)  dsp f32 @ [3M,3.125M)
    // Weight frags (72 KiB) live in d_out — fully overwritten by k_warp at the end.
    char* base = (char*)d_ws;
    bf16*  a0  = (bf16*)base;
    bf16*  a1  = (bf16*)(base + (16u << 20));
    bf16*  a2  = (bf16*)base;
    bf16*  f0  = (bf16*)(base + (1u << 20));
    bf16*  f1  = (bf16*)(base + (2u << 20));
    float* dsp = (float*)(base + (3u << 20));
    bf16*  wfr = (bf16*)d_out;   // 4 layers x 9216 bf16 frags

    k_repack<<<144, 256, 0, stream>>>(w1, w2, fw0, fw1, wfr);
    k_stage0<<<dim3(32, 256, 4), dim3(32, 8), 0, stream>>>(fixed, moving, w0, a0);
    k_conv_mfma<true ><<<dim3(16, 32, 4), 256, 0, stream>>>(a0, wfr + 0 * 9216, a1, 256, 256);
    k_conv_mfma<true ><<<dim3( 8, 16, 4), 256, 0, stream>>>(a1, wfr + 1 * 9216, a2, 128, 128);
    k_conv_mfma<false><<<dim3( 4,  8, 4), 256, 0, stream>>>(a2, wfr + 2 * 9216, f0,  64,  64);
    k_conv_mfma<false><<<dim3( 4,  8, 4), 256, 0, stream>>>(f0, wfr + 3 * 9216, f1,  64,  64);
    k_pw<<<64, 256, 0, stream>>>(f1, pw0, pw1, dsp);
    k_warp<<<4096, 256, 0, stream>>>(dsp, moving, (float*)d_out);
}

// Round 6
// 146.650 us; speedup vs baseline: 4.5954x; 1.2194x over previous
//
#include <hip/hip_runtime.h>
#include <hip/hip_bf16.h>

typedef __hip_bfloat16 bf16;
typedef __attribute__((ext_vector_type(8))) short s8v;     // 8 bf16 = 4 VGPRs
typedef __attribute__((ext_vector_type(16))) float f16v;   // MFMA 32x32 accumulator

#define BNS 0.9995003746877732f  // 1/sqrt(1+1e-3)

__device__ __forceinline__ float lrelu(float x) { return x > 0.f ? x : 0.2f * x; }

struct b4 { bf16 a, b, c, d; };
__device__ __forceinline__ float4 load4(const bf16* p) {
    const b4 q = *reinterpret_cast<const b4*>(p);
    return make_float4(__bfloat162float(q.a), __bfloat162float(q.b),
                       __bfloat162float(q.c), __bfloat162float(q.d));
}

// ---------------------------------------------------------------------------
// Weight repack into MFMA B-fragment order Wf[t][lane][j].
// Layers 0..3: f32 [3,3,32,32] convs -> 18 K-steps x 64 lanes x 8  (9216 each)
//   k = t*16 + (lane>>5)*8 + j ; tap = k>>5 ; ci = k&31 ; co = lane&31
// Layer 4 (stage0): f32 [3,3,2,32] -> 2 K-steps (K=32, 18 real + 14 zero)
//   k = s*16 + (lane>>5)*8 + j ; tap = k>>1 ; ci = k&1 ; co = lane&31
// Total 4*9216 + 1024 = 37888 bf16, lives in d_out (overwritten by k_warp).
// ---------------------------------------------------------------------------
__global__ __launch_bounds__(256) void k_repack(const float* __restrict__ wa,
                                                const float* __restrict__ wb,
                                                const float* __restrict__ wc,
                                                const float* __restrict__ wd,
                                                const float* __restrict__ w0,
                                                bf16* __restrict__ wf)
{
    const int idx = blockIdx.x * 256 + threadIdx.x;   // [0, 37888)
    if (idx < 36864) {
        const int layer = idx / 9216;
        const int r = idx - layer * 9216;
        const int j = r & 7;
        const int l = (r >> 3) & 63;
        const int t = r >> 9;                          // [0,18)
        const int k = t * 16 + ((l >> 5) << 3) + j;
        const int tap = k >> 5, ci = k & 31, co = l & 31;
        const float* W = layer == 0 ? wa : layer == 1 ? wb : layer == 2 ? wc : wd;
        wf[idx] = __float2bfloat16(W[(tap * 32 + ci) * 32 + co]);
    } else {
        const int r = idx - 36864;                     // [0,1024)
        const int j = r & 7;
        const int l = (r >> 3) & 63;
        const int s = r >> 9;                          // 0 or 1
        const int k = s * 16 + ((l >> 5) << 3) + j;
        const int co = l & 31;
        const float v = (k < 18) ? w0[(k >> 1) * 64 + (k & 1) * 32 + co] : 0.f;
        wf[idx] = __float2bfloat16(v);
    }
}

// ---------------------------------------------------------------------------
// Stage 0 via MFMA: concat(fixed,moving) -> conv3x3 (2->32) -> BN*lrelu -> pool
// GEMM: M = pre-pool pixels (512x512), N = 32 co, K = 18 pad 32 (2 MFMA steps).
// LDS: one uint per tile pixel = packed (bf16 fx, bf16 mv); the A-fragment for
// (step s, half h) is simply the lane's packed patch words [s*8+h*4 .. +3].
// Block = 4 waves = 8x16 pre-pool tile -> pooled 4x8. Grid (32,64,4).
// ---------------------------------------------------------------------------
__global__ __launch_bounds__(256) void k_stage0_mfma(const float* __restrict__ fx,
                                                     const float* __restrict__ mv,
                                                     const bf16* __restrict__ wf,
                                                     bf16* __restrict__ out)
{
    __shared__ uint lds[180];  // [row 0..9][col 0..17] packed bf16x2
    const int tid  = threadIdx.x;
    const int lane = tid & 63;
    const int wv   = tid >> 6;
    const int x0 = blockIdx.x * 16;
    const int y0 = blockIdx.y * 8;
    const int b  = blockIdx.z;

    if (tid < 180) {
        const int row = tid / 18, col = tid - row * 18;
        const int gy = y0 - 1 + row, gx = x0 - 1 + col;
        float vf = 0.f, vm = 0.f;
        if ((unsigned)gy < 512u && (unsigned)gx < 512u) {
            const size_t idx = ((size_t)b * 512 + gy) * 512 + gx;
            vf = fx[idx]; vm = mv[idx];
        }
        union { bf16 h[2]; uint u; } pk;
        pk.h[0] = __float2bfloat16(vf);   // ci=0 : fixed
        pk.h[1] = __float2bfloat16(vm);   // ci=1 : moving
        lds[tid] = pk.u;
    }
    __syncthreads();

    const int m  = lane & 31;   // pixel within wave tile: m = dy*16 + xx
    const int h  = lane >> 5;
    const int dy = m >> 4;
    const int xx = m & 15;
    const int rbase = 2 * wv + dy;

    uint p[16];
#pragma unroll
    for (int i = 9; i < 16; ++i) p[i] = 0u;
#pragma unroll
    for (int ky = 0; ky < 3; ++ky)
#pragma unroll
        for (int kx = 0; kx < 3; ++kx)
            p[ky * 3 + kx] = lds[(rbase + ky) * 18 + xx + kx];

    f16v acc;
#pragma unroll
    for (int i = 0; i < 16; ++i) acc[i] = 0.f;

#pragma unroll
    for (int s = 0; s < 2; ++s) {
        union { uint u[4]; s8v v; } af;
#pragma unroll
        for (int q = 0; q < 4; ++q) af.u[q] = p[s * 8 + h * 4 + q];
        const s8v bfg = *reinterpret_cast<const s8v*>(&wf[(s * 64 + lane) * 8]);
        acc = __builtin_amdgcn_mfma_f32_32x32x16_bf16(af.v, bfg, acc, 0, 0, 0);
    }

    // in-register 2x2 avgpool epilogue (proven mapping from k_conv_mfma)
    const int co = lane & 31;
    const int prow = blockIdx.y * 4 + wv;
#pragma unroll
    for (int q = 0; q < 4; ++q) {
        const int base = ((q & 1) << 1) + ((q >> 1) << 2);
        const float s = lrelu(BNS * acc[base])     + lrelu(BNS * acc[base + 1])
                      + lrelu(BNS * acc[base + 8]) + lrelu(BNS * acc[base + 9]);
        const int c = (q & 1) + 2 * h + ((q >> 1) << 2);
        out[(((size_t)b * 256 + prow) * 256 + (blockIdx.x * 8 + c)) * 32 + co] =
            __float2bfloat16(0.25f * s);
    }
}

// ---------------------------------------------------------------------------
// MFMA implicit-GEMM conv3x3 (32->32) SAME -> BN*lrelu [-> avgpool2]
// ---------------------------------------------------------------------------
template <bool POOL>
__global__ __launch_bounds__(256) void k_conv_mfma(const bf16* __restrict__ in,
                                                   const bf16* __restrict__ wf,
                                                   bf16* __restrict__ out,
                                                   int Hi, int Wi)
{
    __shared__ __align__(16) short lds[7200];  // 180 pixels x 40 shorts (32 ci + pad)
    const int tid  = threadIdx.x;
    const int lane = tid & 63;
    const int wv   = tid >> 6;
    const int x0 = blockIdx.x * 16;
    const int y0 = blockIdx.y * 8;
    const int b  = blockIdx.z;

    for (int i = tid; i < 1440; i += 256) {
        const int c4 = i & 7;
        const int p  = i >> 3;           // [0,180)
        const int row = p / 18, col = p - row * 18;
        const int gy = y0 - 1 + row, gx = x0 - 1 + col;
        uint2 v = make_uint2(0u, 0u);
        if ((unsigned)gy < (unsigned)Hi && (unsigned)gx < (unsigned)Wi)
            v = *reinterpret_cast<const uint2*>(&in[(((size_t)b * Hi + gy) * Wi + gx) * 32 + c4 * 4]);
        *reinterpret_cast<uint2*>(&lds[p * 40 + c4 * 4]) = v;
    }
    __syncthreads();

    const int m  = lane & 31;   // GEMM row = pixel: m = dy*16 + x
    const int h  = lane >> 5;
    const int dy = m >> 4;
    const int xx = m & 15;
    const int rbase = 2 * wv + dy;

    f16v acc;
#pragma unroll
    for (int i = 0; i < 16; ++i) acc[i] = 0.f;

#pragma unroll
    for (int t = 0; t < 18; ++t) {
        const int tap = t >> 1;
        const int ky = tap / 3, kx = tap % 3;
        const int ci_ofs = ((t & 1) << 4) + (h << 3);
        const s8v a = *reinterpret_cast<const s8v*>(
            &lds[((rbase + ky) * 18 + (xx + kx)) * 40 + ci_ofs]);
        const s8v bf = *reinterpret_cast<const s8v*>(&wf[(t * 64 + lane) * 8]);
        acc = __builtin_amdgcn_mfma_f32_32x32x16_bf16(a, bf, acc, 0, 0, 0);
    }

    const int co = lane & 31;
    if (POOL) {
        const int Ho = Hi >> 1, Wo = Wi >> 1;
        const int prow = blockIdx.y * 4 + wv;
#pragma unroll
        for (int q = 0; q < 4; ++q) {
            const int base = ((q & 1) << 1) + ((q >> 1) << 2);
            const float s = lrelu(BNS * acc[base])     + lrelu(BNS * acc[base + 1])
                          + lrelu(BNS * acc[base + 8]) + lrelu(BNS * acc[base + 9]);
            const int c = (q & 1) + 2 * h + ((q >> 1) << 2);
            out[(((size_t)b * Ho + prow) * Wo + (blockIdx.x * 8 + c)) * 32 + co] =
                __float2bfloat16(0.25f * s);
        }
    } else {
#pragma unroll
        for (int r = 0; r < 16; ++r) {
            const int mm = (r & 3) + ((r >> 2) << 3) + (h << 2);
            const int gy = y0 + 2 * wv + (mm >> 4);
            const int gx = x0 + (mm & 15);
            out[(((size_t)b * Hi + gy) * Wi + gx) * 32 + co] =
                __float2bfloat16(lrelu(BNS * acc[r]));
        }
    }
}

// ---------------------------------------------------------------------------
// Fused pw0 (1x1 32->32, lrelu, NO BN) + pw1 (1x1 32->2) -> disp [4,64,64,2] f32
// ---------------------------------------------------------------------------
__global__ __launch_bounds__(256) void k_pw(const bf16* __restrict__ in,
                                            const float* __restrict__ pw0,
                                            const float* __restrict__ pw1,
                                            float* __restrict__ disp)
{
    __shared__ float w0t[1024];  // [co][ci]
    __shared__ float w1s[64];    // [co][c]
    const int tid = threadIdx.x;
    for (int i = tid; i < 1024; i += 256) {
        const int ci = i >> 5, co = i & 31;
        w0t[co * 32 + ci] = pw0[i];
    }
    if (tid < 64) w1s[tid] = pw1[tid];
    __syncthreads();

    const int p = blockIdx.x * 256 + tid;  // 16384 pixels
    float4 iv[8];
#pragma unroll
    for (int g = 0; g < 8; ++g)
        iv[g] = load4(&in[(size_t)p * 32 + g * 4]);

    float d0 = 0.f, d1 = 0.f;
#pragma unroll 4
    for (int co = 0; co < 32; ++co) {
        float s = 0.f;
#pragma unroll
        for (int g = 0; g < 8; ++g) {
            const float4 wv = *reinterpret_cast<const float4*>(&w0t[co * 32 + g * 4]);
            s += iv[g].x * wv.x + iv[g].y * wv.y + iv[g].z * wv.z + iv[g].w * wv.w;
        }
        const float p0 = lrelu(s);  // pw0 has NO BN scale
        d0 += p0 * w1s[co * 2 + 0];
        d1 += p0 * w1s[co * 2 + 1];
    }
    disp[(size_t)p * 2 + 0] = d0;
    disp[(size_t)p * 2 + 1] = d1;
}

// ---------------------------------------------------------------------------
// B-spline upsample + bilinear warp + pack outputs (f32 d_out).
// ---------------------------------------------------------------------------
__global__ __launch_bounds__(256) void k_warp(const float* __restrict__ disp,
                                              const float* __restrict__ mv,
                                              float* __restrict__ out)
{
    const int idx = blockIdx.x * 256 + threadIdx.x;  // [0, 1048576)
    const int b = idx >> 18;
    const int h = (idx >> 9) & 511;
    const int w = idx & 511;

    const float xg = fminf(w * 0.125f, 63.0f);
    const float yg = fminf(h * 0.125f, 63.0f);
    const int ii = w >> 3, jj = h >> 3;
    const float u = xg * 0.015625f, v = yg * 0.015625f;

    const float u2 = u * u, u3 = u2 * u;
    const float v2 = v * v, v3 = v2 * v;
    const float Bu[4] = {-u3 + 3.f * u2 - 3.f * u + 1.f,
                         3.f * u3 - 6.f * u2 + 4.f,
                         -3.f * u3 + 3.f * u2 + 3.f * u + 1.f,
                         u3};
    const float Bv[4] = {-v3 + 3.f * v2 - 3.f * v + 1.f,
                         3.f * v3 - 6.f * v2 + 4.f,
                         -3.f * v3 + 3.f * v2 + 3.f * v + 1.f,
                         v3};

    float s0 = 0.f, s1 = 0.f;
#pragma unroll
    for (int m = 0; m < 4; ++m) {
        const int gy = jj + m - 1;
        float r0 = 0.f, r1 = 0.f;
        if ((unsigned)gy < 64u) {
#pragma unroll
            for (int n = 0; n < 4; ++n) {
                const int gx = ii + n - 1;
                if ((unsigned)gx < 64u) {
                    const size_t di = (((size_t)b * 64 + gy) * 64 + gx) * 2;
                    r0 += Bv[n] * disp[di];
                    r1 += Bv[n] * disp[di + 1];
                }
            }
        }
        s0 += Bu[m] * r0;  // B_u pairs with the row-offset axis, per reference
        s1 += Bu[m] * r1;
    }
    const float wx = s0 + (float)w;
    const float wy = s1 + (float)h;

    const float fx = floorf(wx), fy = floorf(wy);
    const float x0 = fminf(fmaxf(fx, 0.f), 511.f);
    const float x1 = fminf(fmaxf(fx + 1.f, 0.f), 511.f);
    const float y0 = fminf(fmaxf(fy, 0.f), 511.f);
    const float y1 = fminf(fmaxf(fy + 1.f, 0.f), 511.f);
    const int x0i = (int)x0, x1i = (int)x1, y0i = (int)y0, y1i = (int)y1;

    float ov;
    if (x0i == x1i || y0i == y1i) {
        ov = 0.f;  // exact result of the reference's cancelling arithmetic
    } else {
        const size_t bb = (size_t)b * 262144;
        const float Q1 = mv[bb + (size_t)y0i * 512 + x0i];
        const float Q2 = mv[bb + (size_t)y1i * 512 + x0i];
        const float Q3 = mv[bb + (size_t)y0i * 512 + x1i];
        const float Q4 = mv[bb + (size_t)y1i * 512 + x1i];
        const float invdx = 1.f / (x1 - x0 + 1e-5f);
        const float wxr = (x1 - wx) * invdx, wxl = (wx - x0) * invdx;
        const float R1 = wxr * Q1 + wxl * Q3;
        const float R2 = wxr * Q2 + wxl * Q4;
        const float invdy = 1.f / (y1 - y0 + 1e-5f);
        ov = (y1 - wy) * invdy * R1 + (wy - y0) * invdy * R2;
    }

    out[idx] = ov;                                          // warped [B,H,W,1]
    const size_t gbase = 1048576;                           // grid region
    out[gbase + (size_t)(b * 2 + 0) * 262144 + (size_t)h * 512 + w] = wx;
    out[gbase + (size_t)(b * 2 + 1) * 262144 + (size_t)h * 512 + w] = wy;
}

// ---------------------------------------------------------------------------
extern "C" void kernel_launch(void* const* d_in, const int* in_sizes, int n_in,
                              void* d_out, int out_size, void* d_ws, size_t ws_size,
                              hipStream_t stream) {
    (void)in_sizes; (void)n_in; (void)out_size; (void)ws_size;
    const float* fixed  = (const float*)d_in[0];
    const float* moving = (const float*)d_in[1];
    const float* w0  = (const float*)d_in[2];
    const float* w1  = (const float*)d_in[3];
    const float* w2  = (const float*)d_in[4];
    const float* fw0 = (const float*)d_in[5];
    const float* fw1 = (const float*)d_in[6];
    const float* pw0 = (const float*)d_in[7];
    const float* pw1 = (const float*)d_in[8];

    // d_ws (max 20 MiB, proven safe):
    //   a0 bf16 [4,256,256,32] @ [0,16M)    a1 bf16 [4,128,128,32] @ [16M,20M)
    //   a2 bf16 @ [0,1M) (a0 dead)  f0 @ [1M,2M)  f1 @ [2M,3M)  dsp f32 @ [3M,3.125M)
    // Weight frags (74 KiB) live in d_out — fully overwritten by k_warp at the end.
    char* base = (char*)d_ws;
    bf16*  a0  = (bf16*)base;
    bf16*  a1  = (bf16*)(base + (16u << 20));
    bf16*  a2  = (bf16*)base;
    bf16*  f0  = (bf16*)(base + (1u << 20));
    bf16*  f1  = (bf16*)(base + (2u << 20));
    float* dsp = (float*)(base + (3u << 20));
    bf16*  wfr = (bf16*)d_out;   // 4x9216 conv frags + 1024 stage0 frags

    k_repack<<<148, 256, 0, stream>>>(w1, w2, fw0, fw1, w0, wfr);
    k_stage0_mfma<<<dim3(32, 64, 4), 256, 0, stream>>>(fixed, moving, wfr + 36864, a0);
    k_conv_mfma<true ><<<dim3(16, 32, 4), 256, 0, stream>>>(a0, wfr + 0 * 9216, a1, 256, 256);
    k_conv_mfma<true ><<<dim3( 8, 16, 4), 256, 0, stream>>>(a1, wfr + 1 * 9216, a2, 128, 128);
    k_conv_mfma<false><<<dim3( 4,  8, 4), 256, 0, stream>>>(a2, wfr + 2 * 9216, f0,  64,  64);
    k_conv_mfma<false><<<dim3( 4,  8, 4), 256, 0, stream>>>(f0, wfr + 3 * 9216, f1,  64,  64);
    k_pw<<<64, 256, 0, stream>>>(f1, pw0, pw1, dsp);
    k_warp<<<4096, 256, 0, stream>>>(dsp, moving, (float*)d_out);
}

// Round 8
// 132.627 us; speedup vs baseline: 5.0813x; 1.1057x over previous
//
#include <hip/hip_runtime.h>
#include <hip/hip_bf16.h>

typedef __hip_bfloat16 bf16;
typedef __attribute__((ext_vector_type(8))) short s8v;     // 8 bf16 = 4 VGPRs
typedef __attribute__((ext_vector_type(16))) float f16v;   // MFMA 32x32 accumulator

#define BNS 0.9995003746877732f  // 1/sqrt(1+1e-3)

__device__ __forceinline__ float lrelu(float x) { return x > 0.f ? x : 0.2f * x; }

struct b4 { bf16 a, b, c, d; };
__device__ __forceinline__ float4 load4(const bf16* p) {
    const b4 q = *reinterpret_cast<const b4*>(p);
    return make_float4(__bfloat162float(q.a), __bfloat162float(q.b),
                       __bfloat162float(q.c), __bfloat162float(q.d));
}

// 18-step conv3x3 (32ci) MFMA K-loop over an LDS tile with row stride `ldw`
// pixels (px stride 40 shorts). (pi,pj) = patch top-left in LDS-local coords.
__device__ __forceinline__ f16v conv18(const short* lds, int ldw, int pi, int pj,
                                       int h, const bf16* __restrict__ wf, int lane)
{
    f16v acc;
#pragma unroll
    for (int i = 0; i < 16; ++i) acc[i] = 0.f;
#pragma unroll
    for (int t = 0; t < 18; ++t) {
        const int tap = t >> 1;
        const int ky = tap / 3, kx = tap % 3;
        const int ci_ofs = ((t & 1) << 4) + (h << 3);
        const s8v a = *reinterpret_cast<const s8v*>(
            &lds[((pi + ky) * ldw + (pj + kx)) * 40 + ci_ofs]);
        const s8v bfg = *reinterpret_cast<const s8v*>(&wf[(t * 64 + lane) * 8]);
        acc = __builtin_amdgcn_mfma_f32_32x32x16_bf16(a, bfg, acc, 0, 0, 0);
    }
    return acc;
}

// ---------------------------------------------------------------------------
// Weight repack into MFMA B-fragment order Wf[t][lane][j].
// Layers 0..3 (w1,w2,fw0,fw1): [3,3,32,32] -> 18 steps (9216 each)
// Layer 4 (stage0 w0): [3,3,2,32] -> 2 steps, K=18 pad 32 (1024)
// ---------------------------------------------------------------------------
__global__ __launch_bounds__(256) void k_repack(const float* __restrict__ wa,
                                                const float* __restrict__ wb,
                                                const float* __restrict__ wc,
                                                const float* __restrict__ wd,
                                                const float* __restrict__ w0,
                                                bf16* __restrict__ wf)
{
    const int idx = blockIdx.x * 256 + threadIdx.x;   // [0, 37888)
    if (idx < 36864) {
        const int layer = idx / 9216;
        const int r = idx - layer * 9216;
        const int j = r & 7;
        const int l = (r >> 3) & 63;
        const int t = r >> 9;
        const int k = t * 16 + ((l >> 5) << 3) + j;
        const int tap = k >> 5, ci = k & 31, co = l & 31;
        const float* W = layer == 0 ? wa : layer == 1 ? wb : layer == 2 ? wc : wd;
        wf[idx] = __float2bfloat16(W[(tap * 32 + ci) * 32 + co]);
    } else {
        const int r = idx - 36864;
        const int j = r & 7;
        const int l = (r >> 3) & 63;
        const int s = r >> 9;
        const int k = s * 16 + ((l >> 5) << 3) + j;
        const int co = l & 31;
        const float v = (k < 18) ? w0[(k >> 1) * 64 + (k & 1) * 32 + co] : 0.f;
        wf[idx] = __float2bfloat16(v);
    }
}

// ---------------------------------------------------------------------------
// FRONT: stage0 (conv2ch->32 + BN lrelu + pool) fused with conv1 (+pool) -> a1
// Block -> a1 tile 4x8 at (by*4, bx*8). In-LDS a0 region 10x18 recomputed from
// raw 22x38 packed (bf16 fx, bf16 mv) patch. Grid (16,32,4).
// ---------------------------------------------------------------------------
__global__ __launch_bounds__(256) void k_front(const float* __restrict__ fx,
                                               const float* __restrict__ mv,
                                               const bf16* __restrict__ wfs0,
                                               const bf16* __restrict__ wfc1,
                                               bf16* __restrict__ a1)
{
    __shared__ uint rawL[864];                    // 22 x 38 (+ zero pad)
    __shared__ __align__(16) short a0L[7200];     // 10 x 18 px x 40 shorts
    const int tid  = threadIdx.x;
    const int lane = tid & 63;
    const int wv   = tid >> 6;
    const int h  = lane >> 5;
    const int m  = lane & 31;
    const int dy = m >> 4;
    const int xx = m & 15;
    const int x0 = blockIdx.x * 16;   // a0-space tile origin (pre-pool-256)
    const int y0 = blockIdx.y * 8;
    const int b  = blockIdx.z;
    const int co = lane & 31;

    // stage raw region: rows 2y0-3 .. 2y0+18, cols 2x0-3 .. 2x0+34
    for (int i = tid; i < 864; i += 256) {
        uint pk = 0u;
        if (i < 836) {
            const int row = i / 38, col = i - (i / 38) * 38;
            const int gy = 2 * y0 - 3 + row, gx = 2 * x0 - 3 + col;
            if ((unsigned)gy < 512u && (unsigned)gx < 512u) {
                const size_t idx = ((size_t)b * 512 + gy) * 512 + gx;
                union { bf16 hh[2]; uint u; } p;
                p.hh[0] = __float2bfloat16(fx[idx]);   // ci=0
                p.hh[1] = __float2bfloat16(mv[idx]);   // ci=1
                pk = p.u;
            }
        }
        rawL[i] = pk;
    }
    __syncthreads();

    // ---- phase 1: stage0 -> a0L (10x18, zero at 256-image OOB) ----
    const s8v b0 = *reinterpret_cast<const s8v*>(&wfs0[(0 * 64 + lane) * 8]);
    const s8v b1 = *reinterpret_cast<const s8v*>(&wfs0[(1 * 64 + lane) * 8]);
    for (int T = wv; T < 30; T += 4) {
        const int r = T / 3, g = T - 3 * r;       // row-pair, col-group
        const int pr = 2 * r + dy, pc = g * 16 + xx;
        uint p[9];
#pragma unroll
        for (int ky = 0; ky < 3; ++ky)
#pragma unroll
            for (int kx = 0; kx < 3; ++kx)
                p[ky * 3 + kx] = rawL[(pr + ky) * 38 + pc + kx];

        f16v acc;
#pragma unroll
        for (int i = 0; i < 16; ++i) acc[i] = 0.f;
        union { uint u[4]; s8v v; } a0f, a1f;
#pragma unroll
        for (int q = 0; q < 4; ++q) a0f.u[q] = p[h * 4 + q];      // taps h*4..h*4+3
        a1f.u[0] = (h == 0) ? p[8] : 0u;                           // tap 8
        a1f.u[1] = 0u; a1f.u[2] = 0u; a1f.u[3] = 0u;
        acc = __builtin_amdgcn_mfma_f32_32x32x16_bf16(a0f.v, b0, acc, 0, 0, 0);
        acc = __builtin_amdgcn_mfma_f32_32x32x16_bf16(a1f.v, b1, acc, 0, 0, 0);

        // in-register pool -> a0L px (row r, col g*8+c)
#pragma unroll
        for (int q = 0; q < 4; ++q) {
            const int base = ((q & 1) << 1) + ((q >> 1) << 2);
            const float s = lrelu(BNS * acc[base])     + lrelu(BNS * acc[base + 1])
                          + lrelu(BNS * acc[base + 8]) + lrelu(BNS * acc[base + 9]);
            const int col = g * 8 + ((q & 1) + 2 * h + ((q >> 1) << 2));
            if (col < 18) {
                const int gy0 = y0 - 1 + r, gx0 = x0 - 1 + col;
                const float val = ((unsigned)gy0 < 256u && (unsigned)gx0 < 256u)
                                  ? 0.25f * s : 0.f;
                a0L[(r * 18 + col) * 40 + co] = __float2bfloat16(val);
            }
        }
    }
    __syncthreads();

    // ---- phase 2: conv1 + pool -> a1 global (proven body) ----
    const f16v acc = conv18(a0L, 18, 2 * wv + dy, xx, h, wfc1, lane);
    const int prow = blockIdx.y * 4 + wv;
#pragma unroll
    for (int q = 0; q < 4; ++q) {
        const int base = ((q & 1) << 1) + ((q >> 1) << 2);
        const float s = lrelu(BNS * acc[base])     + lrelu(BNS * acc[base + 1])
                      + lrelu(BNS * acc[base + 8]) + lrelu(BNS * acc[base + 9]);
        const int c = (q & 1) + 2 * h + ((q >> 1) << 2);
        a1[(((size_t)b * 128 + prow) * 128 + (blockIdx.x * 8 + c)) * 32 + co] =
            __float2bfloat16(0.25f * s);
    }
}

// ---------------------------------------------------------------------------
// conv2: MFMA implicit-GEMM conv3x3 (32->32) -> BN lrelu -> pool (proven).
// ---------------------------------------------------------------------------
__global__ __launch_bounds__(256) void k_conv2(const bf16* __restrict__ in,
                                               const bf16* __restrict__ wf,
                                               bf16* __restrict__ out,
                                               int Hi, int Wi)
{
    __shared__ __align__(16) short lds[7200];  // 180 px x 40 shorts
    const int tid  = threadIdx.x;
    const int lane = tid & 63;
    const int wv   = tid >> 6;
    const int x0 = blockIdx.x * 16;
    const int y0 = blockIdx.y * 8;
    const int b  = blockIdx.z;

    for (int i = tid; i < 1440; i += 256) {
        const int c4 = i & 7;
        const int p  = i >> 3;
        const int row = p / 18, col = p - row * 18;
        const int gy = y0 - 1 + row, gx = x0 - 1 + col;
        uint2 v = make_uint2(0u, 0u);
        if ((unsigned)gy < (unsigned)Hi && (unsigned)gx < (unsigned)Wi)
            v = *reinterpret_cast<const uint2*>(&in[(((size_t)b * Hi + gy) * Wi + gx) * 32 + c4 * 4]);
        *reinterpret_cast<uint2*>(&lds[p * 40 + c4 * 4]) = v;
    }
    __syncthreads();

    const int m  = lane & 31;
    const int h  = lane >> 5;
    const int dy = m >> 4;
    const int xx = m & 15;

    const f16v acc = conv18(lds, 18, 2 * wv + dy, xx, h, wf, lane);

    const int co = lane & 31;
    const int Ho = Hi >> 1, Wo = Wi >> 1;
    const int prow = blockIdx.y * 4 + wv;
#pragma unroll
    for (int q = 0; q < 4; ++q) {
        const int base = ((q & 1) << 1) + ((q >> 1) << 2);
        const float s = lrelu(BNS * acc[base])     + lrelu(BNS * acc[base + 1])
                      + lrelu(BNS * acc[base + 8]) + lrelu(BNS * acc[base + 9]);
        const int c = (q & 1) + 2 * h + ((q >> 1) << 2);
        out[(((size_t)b * Ho + prow) * Wo + (blockIdx.x * 8 + c)) * 32 + co] =
            __float2bfloat16(0.25f * s);
    }
}

// ---------------------------------------------------------------------------
// TAIL: conv3 -> conv4 -> pw0/pw1 -> b-spline upsample -> bilinear warp.
// Block -> 64x64 output tile at (by*64, bx*64). Grid (8,8,4).
// In-LDS: a2 15x15(+pad), f0 13x13 (zero-masked at image OOB, like the
// reference's zero conv padding), f1 11x11, dsp 11x11 (zero at OOB -> exact
// b-spline pad taps). 16 output px per thread.
// ---------------------------------------------------------------------------
__global__ __launch_bounds__(256) void k_tail(const bf16* __restrict__ a2,
                                              const bf16* __restrict__ wf2,
                                              const bf16* __restrict__ wf3,
                                              const float* __restrict__ pw0,
                                              const float* __restrict__ pw1,
                                              const float* __restrict__ mv,
                                              float* __restrict__ out)
{
    __shared__ __align__(16) short a2L[288 * 40];   // 16r x 18c
    __shared__ __align__(16) short f0L[252 * 40];   // 14r x 18c
    __shared__ __align__(16) short f1L[121 * 40];   // 11 x 11
    __shared__ float dspL[121 * 2];
    __shared__ float w0t[1024];
    __shared__ float w1s[64];

    const int tid  = threadIdx.x;
    const int lane = tid & 63;
    const int wv   = tid >> 6;
    const int h  = lane >> 5;
    const int dy = (lane & 31) >> 4;
    const int xx = lane & 15;
    const int co = lane & 31;
    const int bx = blockIdx.x, by = blockIdx.y, b = blockIdx.z;
    const int Dy = by * 8 - 1, Dx = bx * 8 - 1;    // dsp/f1 region origin

    // phase A: stage a2 region (15x15 real in 16x18 zeroed), pw weights,
    // and zero f0L pad cols 16,17.
    for (int i = tid; i < 2304; i += 256) {
        const int c4 = i & 7;
        const int p  = i >> 3;
        const int row = p / 18, col = p - row * 18;
        const int gy = Dy - 2 + row, gx = Dx - 2 + col;
        uint2 v = make_uint2(0u, 0u);
        if (row < 15 && col < 15 && (unsigned)gy < 64u && (unsigned)gx < 64u)
            v = *reinterpret_cast<const uint2*>(&a2[(((size_t)b * 64 + gy) * 64 + gx) * 32 + c4 * 4]);
        *reinterpret_cast<uint2*>(&a2L[p * 40 + c4 * 4]) = v;
    }
    for (int i = tid; i < 560; i += 256) {           // 28 px x 20 uints
        const int p28 = i / 20, w = i - (i / 20) * 20;
        const int row = p28 >> 1, col = 16 + (p28 & 1);
        reinterpret_cast<uint*>(f0L)[(row * 18 + col) * 20 + w] = 0u;
    }
    for (int i = tid; i < 1024; i += 256) {
        const int ci = i >> 5, c = i & 31;
        w0t[c * 32 + ci] = pw0[i];
    }
    if (tid < 64) w1s[tid] = pw1[tid];
    __syncthreads();

    // phase B: f0 = conv3(a2), region 13x13 at (Dy-1, Dx-1)
    for (int T = wv; T < 7; T += 4) {
        const f16v acc = conv18(a2L, 18, 2 * T + dy, xx, h, wf2, lane);
#pragma unroll
        for (int r = 0; r < 16; ++r) {
            const int row32 = (r & 3) + ((r >> 2) << 3) + (h << 2);
            const int i = 2 * T + (row32 >> 4);
            const int j = row32 & 15;
            const int gy = Dy - 1 + i, gx = Dx - 1 + j;
            const float val = (i < 13 && j < 13 &&
                               (unsigned)gy < 64u && (unsigned)gx < 64u)
                              ? lrelu(BNS * acc[r]) : 0.f;
            f0L[(i * 18 + j) * 40 + co] = __float2bfloat16(val);
        }
    }
    __syncthreads();

    // phase C: f1 = conv4(f0), region 11x11 at (Dy, Dx)
    for (int T = wv; T < 6; T += 4) {
        const f16v acc = conv18(f0L, 18, 2 * T + dy, xx, h, wf3, lane);
#pragma unroll
        for (int r = 0; r < 16; ++r) {
            const int row32 = (r & 3) + ((r >> 2) << 3) + (h << 2);
            const int i = 2 * T + (row32 >> 4);
            const int j = row32 & 15;
            if (i < 11 && j < 11)
                f1L[(i * 11 + j) * 40 + co] = __float2bfloat16(lrelu(BNS * acc[r]));
        }
    }
    __syncthreads();

    // phase D: pw0 (lrelu, no BN) + pw1 -> dspL (zero at image OOB)
    if (tid < 121) {
        const int i = tid / 11, j = tid - (tid / 11) * 11;
        const int gy = Dy + i, gx = Dx + j;
        float d0 = 0.f, d1 = 0.f;
        if ((unsigned)gy < 64u && (unsigned)gx < 64u) {
            float4 iv[8];
#pragma unroll
            for (int g = 0; g < 8; ++g)
                iv[g] = load4(reinterpret_cast<const bf16*>(&f1L[tid * 40 + g * 4]));
#pragma unroll 4
            for (int c = 0; c < 32; ++c) {
                float s = 0.f;
#pragma unroll
                for (int g = 0; g < 8; ++g) {
                    const float4 wvv = *reinterpret_cast<const float4*>(&w0t[c * 32 + g * 4]);
                    s += iv[g].x * wvv.x + iv[g].y * wvv.y + iv[g].z * wvv.z + iv[g].w * wvv.w;
                }
                const float p0 = lrelu(s);
                d0 += p0 * w1s[c * 2 + 0];
                d1 += p0 * w1s[c * 2 + 1];
            }
        }
        dspL[tid * 2 + 0] = d0;
        dspL[tid * 2 + 1] = d1;
    }
    __syncthreads();

    // phase E: b-spline + bilinear warp, 16 px/thread
    const int hy = by * 64, hx = bx * 64;
#pragma unroll 2
    for (int k = 0; k < 16; ++k) {
        const int l = k * 256 + tid;
        const int hh = hy + (l >> 6);
        const int ww = hx + (l & 63);

        const float xg = fminf(ww * 0.125f, 63.0f);
        const float yg = fminf(hh * 0.125f, 63.0f);
        const float u = xg * 0.015625f, v = yg * 0.015625f;
        const int lr = (hh >> 3) - by * 8 + 1;    // local dsp row of jj
        const int lc = (ww >> 3) - bx * 8 + 1;

        const float u2 = u * u, u3 = u2 * u;
        const float v2 = v * v, v3 = v2 * v;
        const float Bu[4] = {-u3 + 3.f * u2 - 3.f * u + 1.f,
                             3.f * u3 - 6.f * u2 + 4.f,
                             -3.f * u3 + 3.f * u2 + 3.f * u + 1.f,
                             u3};
        const float Bv[4] = {-v3 + 3.f * v2 - 3.f * v + 1.f,
                             3.f * v3 - 6.f * v2 + 4.f,
                             -3.f * v3 + 3.f * v2 + 3.f * v + 1.f,
                             v3};

        float s0 = 0.f, s1 = 0.f;
#pragma unroll
        for (int mm = 0; mm < 4; ++mm) {
            const int row = lr + mm - 1;          // in [0,10]
            float r0 = 0.f, r1 = 0.f;
#pragma unroll
            for (int nn = 0; nn < 4; ++nn) {
                const int col = lc + nn - 1;      // in [0,10]
                const float2 d = *reinterpret_cast<const float2*>(&dspL[(row * 11 + col) * 2]);
                r0 += Bv[nn] * d.x;
                r1 += Bv[nn] * d.y;
            }
            s0 += Bu[mm] * r0;                     // B_u pairs with row axis
            s1 += Bu[mm] * r1;
        }
        const float wx = s0 + (float)ww;
        const float wy = s1 + (float)hh;

        const float fxx = floorf(wx), fyy = floorf(wy);
        const float x0 = fminf(fmaxf(fxx, 0.f), 511.f);
        const float x1 = fminf(fmaxf(fxx + 1.f, 0.f), 511.f);
        const float y0 = fminf(fmaxf(fyy, 0.f), 511.f);
        const float y1 = fminf(fmaxf(fyy + 1.f, 0.f), 511.f);
        const int x0i = (int)x0, x1i = (int)x1, y0i = (int)y0, y1i = (int)y1;

        float ov;
        if (x0i == x1i || y0i == y1i) {
            ov = 0.f;   // exact result of the reference's cancelling arithmetic
        } else {
            const size_t bb = (size_t)b * 262144;
            const float Q1 = mv[bb + (size_t)y0i * 512 + x0i];
            const float Q2 = mv[bb + (size_t)y1i * 512 + x0i];
            const float Q3 = mv[bb + (size_t)y0i * 512 + x1i];
            const float Q4 = mv[bb + (size_t)y1i * 512 + x1i];
            const float invdx = 1.f / (x1 - x0 + 1e-5f);
            const float wxr = (x1 - wx) * invdx, wxl = (wx - x0) * invdx;
            const float R1 = wxr * Q1 + wxl * Q3;
            const float R2 = wxr * Q2 + wxl * Q4;
            const float invdy = 1.f / (y1 - y0 + 1e-5f);
            ov = (y1 - wy) * invdy * R1 + (wy - y0) * invdy * R2;
        }

        const size_t pix = (size_t)hh * 512 + ww;
        out[(size_t)b * 262144 + pix] = ov;                          // warped
        out[1048576 + (size_t)(b * 2 + 0) * 262144 + pix] = wx;      // grid x
        out[1048576 + (size_t)(b * 2 + 1) * 262144 + pix] = wy;      // grid y
    }
}

// ---------------------------------------------------------------------------
extern "C" void kernel_launch(void* const* d_in, const int* in_sizes, int n_in,
                              void* d_out, int out_size, void* d_ws, size_t ws_size,
                              hipStream_t stream) {
    (void)in_sizes; (void)n_in; (void)out_size; (void)ws_size;
    const float* fixed  = (const float*)d_in[0];
    const float* moving = (const float*)d_in[1];
    const float* w0  = (const float*)d_in[2];
    const float* w1  = (const float*)d_in[3];
    const float* w2  = (const float*)d_in[4];
    const float* fw0 = (const float*)d_in[5];
    const float* fw1 = (const float*)d_in[6];
    const float* pw0 = (const float*)d_in[7];
    const float* pw1 = (const float*)d_in[8];

    // d_ws layout (peak 7 MiB, well under the proven 20 MiB):
    //   wfr bf16 37888 frags @ [0, 74KB)
    //   a1  bf16 [4,128,128,32] @ [1M, 5.2M)
    //   a2  bf16 [4,64,64,32]   @ [6M, 7M)
    char* base = (char*)d_ws;
    bf16* wfr = (bf16*)base;
    bf16* a1  = (bf16*)(base + (1u << 20));
    bf16* a2  = (bf16*)(base + (6u << 20));

    k_repack<<<148, 256, 0, stream>>>(w1, w2, fw0, fw1, w0, wfr);
    k_front<<<dim3(16, 32, 4), 256, 0, stream>>>(fixed, moving,
                                                 wfr + 36864, wfr + 0 * 9216, a1);
    k_conv2<<<dim3(8, 16, 4), 256, 0, stream>>>(a1, wfr + 1 * 9216, a2, 128, 128);
    k_tail<<<dim3(8, 8, 4), 256, 0, stream>>>(a2, wfr + 2 * 9216, wfr + 3 * 9216,
                                              pw0, pw1, moving, (float*)d_out);
}

// Round 9
// 132.555 us; speedup vs baseline: 5.0840x; 1.0005x over previous
//
#include <hip/hip_runtime.h>
#include <hip/hip_bf16.h>

typedef __hip_bfloat16 bf16;
typedef __attribute__((ext_vector_type(8))) short s8v;     // 8 bf16 = 4 VGPRs
typedef __attribute__((ext_vector_type(16))) float f16v;   // MFMA 32x32 accumulator

#define BNS 0.9995003746877732f  // 1/sqrt(1+1e-3)

__device__ __forceinline__ float lrelu(float x) { return x > 0.f ? x : 0.2f * x; }

struct b4 { bf16 a, b, c, d; };
__device__ __forceinline__ float4 load4(const bf16* p) {
    const b4 q = *reinterpret_cast<const b4*>(p);
    return make_float4(__bfloat162float(q.a), __bfloat162float(q.b),
                       __bfloat162float(q.c), __bfloat162float(q.d));
}

// 18-step conv3x3 (32ci) MFMA K-loop over an LDS tile with row stride `ldw`
// pixels (px stride 40 shorts). (pi,pj) = patch top-left in LDS-local coords.
__device__ __forceinline__ f16v conv18(const short* lds, int ldw, int pi, int pj,
                                       int h, const bf16* __restrict__ wf, int lane)
{
    f16v acc;
#pragma unroll
    for (int i = 0; i < 16; ++i) acc[i] = 0.f;
#pragma unroll
    for (int t = 0; t < 18; ++t) {
        const int tap = t >> 1;
        const int ky = tap / 3, kx = tap % 3;
        const int ci_ofs = ((t & 1) << 4) + (h << 3);
        const s8v a = *reinterpret_cast<const s8v*>(
            &lds[((pi + ky) * ldw + (pj + kx)) * 40 + ci_ofs]);
        const s8v bfg = *reinterpret_cast<const s8v*>(&wf[(t * 64 + lane) * 8]);
        acc = __builtin_amdgcn_mfma_f32_32x32x16_bf16(a, bfg, acc, 0, 0, 0);
    }
    return acc;
}

// ---------------------------------------------------------------------------
// Weight repack into MFMA B-fragment order Wf[t][lane][j].
// Layers 0..3 (w1,w2,fw0,fw1): [3,3,32,32] -> 18 steps (9216 each)
// Layer 4 (stage0 w0): [3,3,2,32] -> 2 steps, K=18 pad 32 (1024)
// ---------------------------------------------------------------------------
__global__ __launch_bounds__(256) void k_repack(const float* __restrict__ wa,
                                                const float* __restrict__ wb,
                                                const float* __restrict__ wc,
                                                const float* __restrict__ wd,
                                                const float* __restrict__ w0,
                                                bf16* __restrict__ wf)
{
    const int idx = blockIdx.x * 256 + threadIdx.x;   // [0, 37888)
    if (idx < 36864) {
        const int layer = idx / 9216;
        const int r = idx - layer * 9216;
        const int j = r & 7;
        const int l = (r >> 3) & 63;
        const int t = r >> 9;
        const int k = t * 16 + ((l >> 5) << 3) + j;
        const int tap = k >> 5, ci = k & 31, co = l & 31;
        const float* W = layer == 0 ? wa : layer == 1 ? wb : layer == 2 ? wc : wd;
        wf[idx] = __float2bfloat16(W[(tap * 32 + ci) * 32 + co]);
    } else {
        const int r = idx - 36864;
        const int j = r & 7;
        const int l = (r >> 3) & 63;
        const int s = r >> 9;
        const int k = s * 16 + ((l >> 5) << 3) + j;
        const int co = l & 31;
        const float v = (k < 18) ? w0[(k >> 1) * 64 + (k & 1) * 32 + co] : 0.f;
        wf[idx] = __float2bfloat16(v);
    }
}

// ---------------------------------------------------------------------------
// FRONT: stage0 (conv2ch->32 + BN lrelu + pool) fused with conv1 (+pool) -> a1
// Block -> a1 tile 4x8 at (by*4, bx*8). In-LDS a0 region 10x18 recomputed from
// raw 22x38 packed (bf16 fx, bf16 mv) patch. Grid (16,32,4).
// ---------------------------------------------------------------------------
__global__ __launch_bounds__(256) void k_front(const float* __restrict__ fx,
                                               const float* __restrict__ mv,
                                               const bf16* __restrict__ wfs0,
                                               const bf16* __restrict__ wfc1,
                                               bf16* __restrict__ a1)
{
    __shared__ uint rawL[864];                    // 22 x 38 (+ zero pad)
    __shared__ __align__(16) short a0L[7200];     // 10 x 18 px x 40 shorts
    const int tid  = threadIdx.x;
    const int lane = tid & 63;
    const int wv   = tid >> 6;
    const int h  = lane >> 5;
    const int m  = lane & 31;
    const int dy = m >> 4;
    const int xx = m & 15;
    const int x0 = blockIdx.x * 16;   // a0-space tile origin (pre-pool-256)
    const int y0 = blockIdx.y * 8;
    const int b  = blockIdx.z;
    const int co = lane & 31;

    // stage raw region: rows 2y0-3 .. 2y0+18, cols 2x0-3 .. 2x0+34
    for (int i = tid; i < 864; i += 256) {
        uint pk = 0u;
        if (i < 836) {
            const int row = i / 38, col = i - (i / 38) * 38;
            const int gy = 2 * y0 - 3 + row, gx = 2 * x0 - 3 + col;
            if ((unsigned)gy < 512u && (unsigned)gx < 512u) {
                const size_t idx = ((size_t)b * 512 + gy) * 512 + gx;
                union { bf16 hh[2]; uint u; } p;
                p.hh[0] = __float2bfloat16(fx[idx]);   // ci=0
                p.hh[1] = __float2bfloat16(mv[idx]);   // ci=1
                pk = p.u;
            }
        }
        rawL[i] = pk;
    }
    __syncthreads();

    // ---- phase 1: stage0 -> a0L (10x18, zero at 256-image OOB) ----
    const s8v b0 = *reinterpret_cast<const s8v*>(&wfs0[(0 * 64 + lane) * 8]);
    const s8v b1 = *reinterpret_cast<const s8v*>(&wfs0[(1 * 64 + lane) * 8]);
    for (int T = wv; T < 30; T += 4) {
        const int r = T / 3, g = T - 3 * r;       // row-pair, col-group
        const int pr = 2 * r + dy, pc = g * 16 + xx;
        uint p[9];
#pragma unroll
        for (int ky = 0; ky < 3; ++ky)
#pragma unroll
            for (int kx = 0; kx < 3; ++kx)
                p[ky * 3 + kx] = rawL[(pr + ky) * 38 + pc + kx];

        f16v acc;
#pragma unroll
        for (int i = 0; i < 16; ++i) acc[i] = 0.f;
        union { uint u[4]; s8v v; } a0f, a1f;
#pragma unroll
        for (int q = 0; q < 4; ++q) a0f.u[q] = p[h * 4 + q];      // taps h*4..h*4+3
        a1f.u[0] = (h == 0) ? p[8] : 0u;                           // tap 8
        a1f.u[1] = 0u; a1f.u[2] = 0u; a1f.u[3] = 0u;
        acc = __builtin_amdgcn_mfma_f32_32x32x16_bf16(a0f.v, b0, acc, 0, 0, 0);
        acc = __builtin_amdgcn_mfma_f32_32x32x16_bf16(a1f.v, b1, acc, 0, 0, 0);

        // in-register pool -> a0L px (row r, col g*8+c)
#pragma unroll
        for (int q = 0; q < 4; ++q) {
            const int base = ((q & 1) << 1) + ((q >> 1) << 2);
            const float s = lrelu(BNS * acc[base])     + lrelu(BNS * acc[base + 1])
                          + lrelu(BNS * acc[base + 8]) + lrelu(BNS * acc[base + 9]);
            const int col = g * 8 + ((q & 1) + 2 * h + ((q >> 1) << 2));
            if (col < 18) {
                const int gy0 = y0 - 1 + r, gx0 = x0 - 1 + col;
                const float val = ((unsigned)gy0 < 256u && (unsigned)gx0 < 256u)
                                  ? 0.25f * s : 0.f;
                a0L[(r * 18 + col) * 40 + co] = __float2bfloat16(val);
            }
        }
    }
    __syncthreads();

    // ---- phase 2: conv1 + pool -> a1 global (proven body) ----
    const f16v acc = conv18(a0L, 18, 2 * wv + dy, xx, h, wfc1, lane);
    const int prow = blockIdx.y * 4 + wv;
#pragma unroll
    for (int q = 0; q < 4; ++q) {
        const int base = ((q & 1) << 1) + ((q >> 1) << 2);
        const float s = lrelu(BNS * acc[base])     + lrelu(BNS * acc[base + 1])
                      + lrelu(BNS * acc[base + 8]) + lrelu(BNS * acc[base + 9]);
        const int c = (q & 1) + 2 * h + ((q >> 1) << 2);
        a1[(((size_t)b * 128 + prow) * 128 + (blockIdx.x * 8 + c)) * 32 + co] =
            __float2bfloat16(0.25f * s);
    }
}

// ---------------------------------------------------------------------------
// conv2: MFMA implicit-GEMM conv3x3 (32->32) -> BN lrelu -> pool (proven).
// ---------------------------------------------------------------------------
__global__ __launch_bounds__(256) void k_conv2(const bf16* __restrict__ in,
                                               const bf16* __restrict__ wf,
                                               bf16* __restrict__ out,
                                               int Hi, int Wi)
{
    __shared__ __align__(16) short lds[7200];  // 180 px x 40 shorts
    const int tid  = threadIdx.x;
    const int lane = tid & 63;
    const int wv   = tid >> 6;
    const int x0 = blockIdx.x * 16;
    const int y0 = blockIdx.y * 8;
    const int b  = blockIdx.z;

    for (int i = tid; i < 1440; i += 256) {
        const int c4 = i & 7;
        const int p  = i >> 3;
        const int row = p / 18, col = p - row * 18;
        const int gy = y0 - 1 + row, gx = x0 - 1 + col;
        uint2 v = make_uint2(0u, 0u);
        if ((unsigned)gy < (unsigned)Hi && (unsigned)gx < (unsigned)Wi)
            v = *reinterpret_cast<const uint2*>(&in[(((size_t)b * Hi + gy) * Wi + gx) * 32 + c4 * 4]);
        *reinterpret_cast<uint2*>(&lds[p * 40 + c4 * 4]) = v;
    }
    __syncthreads();

    const int m  = lane & 31;
    const int h  = lane >> 5;
    const int dy = m >> 4;
    const int xx = m & 15;

    const f16v acc = conv18(lds, 18, 2 * wv + dy, xx, h, wf, lane);

    const int co = lane & 31;
    const int Ho = Hi >> 1, Wo = Wi >> 1;
    const int prow = blockIdx.y * 4 + wv;
#pragma unroll
    for (int q = 0; q < 4; ++q) {
        const int base = ((q & 1) << 1) + ((q >> 1) << 2);
        const float s = lrelu(BNS * acc[base])     + lrelu(BNS * acc[base + 1])
                      + lrelu(BNS * acc[base + 8]) + lrelu(BNS * acc[base + 9]);
        const int c = (q & 1) + 2 * h + ((q >> 1) << 2);
        out[(((size_t)b * Ho + prow) * Wo + (blockIdx.x * 8 + c)) * 32 + co] =
            __float2bfloat16(0.25f * s);
    }
}

// ---------------------------------------------------------------------------
// TAIL: conv3 -> conv4 -> pw0/pw1 -> b-spline upsample -> bilinear warp.
// Block -> 32x32 output tile at (by*32, bx*32). Grid (16,16,4) = 4 blocks/CU.
// In-LDS: a2 11x11 (12x18 staged), f0 9x9 (10x18, zero-masked at image OOB),
// f1 7x7, dsp 7x7 (zero at OOB -> exact b-spline pad taps). 4 px/thread.
// ---------------------------------------------------------------------------
__global__ __launch_bounds__(256) void k_tail(const bf16* __restrict__ a2,
                                              const bf16* __restrict__ wf2,
                                              const bf16* __restrict__ wf3,
                                              const float* __restrict__ pw0,
                                              const float* __restrict__ pw1,
                                              const float* __restrict__ mv,
                                              float* __restrict__ out)
{
    __shared__ __align__(16) short a2L[216 * 40];   // 12r x 18c
    __shared__ __align__(16) short f0L[180 * 40];   // 10r x 18c
    __shared__ __align__(16) short f1L[49 * 40];    // 7 x 7
    __shared__ float dspL[49 * 2];
    __shared__ float w0t[1024];
    __shared__ float w1s[64];

    const int tid  = threadIdx.x;
    const int lane = tid & 63;
    const int wv   = tid >> 6;
    const int h  = lane >> 5;
    const int dy = (lane & 31) >> 4;
    const int xx = lane & 15;
    const int co = lane & 31;
    const int bx = blockIdx.x, by = blockIdx.y, b = blockIdx.z;
    const int Dy = by * 4 - 1, Dx = bx * 4 - 1;    // dsp/f1 region origin (7x7)

    // phase A: stage a2 region (11x11 real in 12x18 zeroed), pw weights,
    // and zero f0L pad cols 16,17.
    for (int i = tid; i < 1728; i += 256) {         // 216 px x 8 uint2
        const int c4 = i & 7;
        const int p  = i >> 3;
        const int row = p / 18, col = p - row * 18;
        const int gy = Dy - 2 + row, gx = Dx - 2 + col;
        uint2 v = make_uint2(0u, 0u);
        if (row < 11 && col < 11 && (unsigned)gy < 64u && (unsigned)gx < 64u)
            v = *reinterpret_cast<const uint2*>(&a2[(((size_t)b * 64 + gy) * 64 + gx) * 32 + c4 * 4]);
        *reinterpret_cast<uint2*>(&a2L[p * 40 + c4 * 4]) = v;
    }
    for (int i = tid; i < 400; i += 256) {          // 20 px x 20 uints
        const int p20 = i / 20, w = i - (i / 20) * 20;
        const int row = p20 >> 1, col = 16 + (p20 & 1);
        reinterpret_cast<uint*>(f0L)[(row * 18 + col) * 20 + w] = 0u;
    }
    for (int i = tid; i < 1024; i += 256) {
        const int ci = i >> 5, c = i & 31;
        w0t[c * 32 + ci] = pw0[i];
    }
    if (tid < 64) w1s[tid] = pw1[tid];
    __syncthreads();

    // phase B: f0 = conv3(a2), region 9x9 at (Dy-1, Dx-1); buffer rows 0..9
    for (int T = wv; T < 5; T += 4) {
        const f16v acc = conv18(a2L, 18, 2 * T + dy, xx, h, wf2, lane);
#pragma unroll
        for (int r = 0; r < 16; ++r) {
            const int row32 = (r & 3) + ((r >> 2) << 3) + (h << 2);
            const int i = 2 * T + (row32 >> 4);
            const int j = row32 & 15;
            const int gy = Dy - 1 + i, gx = Dx - 1 + j;
            const float val = (i < 9 && j < 9 &&
                               (unsigned)gy < 64u && (unsigned)gx < 64u)
                              ? lrelu(BNS * acc[r]) : 0.f;
            f0L[(i * 18 + j) * 40 + co] = __float2bfloat16(val);
        }
    }
    __syncthreads();

    // phase C: f1 = conv4(f0), region 7x7 at (Dy, Dx)
    if (wv < 4) {
        const int T = wv;
        const f16v acc = conv18(f0L, 18, 2 * T + dy, xx, h, wf3, lane);
#pragma unroll
        for (int r = 0; r < 16; ++r) {
            const int row32 = (r & 3) + ((r >> 2) << 3) + (h << 2);
            const int i = 2 * T + (row32 >> 4);
            const int j = row32 & 15;
            if (i < 7 && j < 7)
                f1L[(i * 7 + j) * 40 + co] = __float2bfloat16(lrelu(BNS * acc[r]));
        }
    }
    __syncthreads();

    // phase D: pw0 (lrelu, no BN) + pw1 -> dspL (zero at image OOB)
    if (tid < 49) {
        const int i = tid / 7, j = tid - (tid / 7) * 7;
        const int gy = Dy + i, gx = Dx + j;
        float d0 = 0.f, d1 = 0.f;
        if ((unsigned)gy < 64u && (unsigned)gx < 64u) {
            float4 iv[8];
#pragma unroll
            for (int g = 0; g < 8; ++g)
                iv[g] = load4(reinterpret_cast<const bf16*>(&f1L[tid * 40 + g * 4]));
#pragma unroll 4
            for (int c = 0; c < 32; ++c) {
                float s = 0.f;
#pragma unroll
                for (int g = 0; g < 8; ++g) {
                    const float4 wvv = *reinterpret_cast<const float4*>(&w0t[c * 32 + g * 4]);
                    s += iv[g].x * wvv.x + iv[g].y * wvv.y + iv[g].z * wvv.z + iv[g].w * wvv.w;
                }
                const float p0 = lrelu(s);
                d0 += p0 * w1s[c * 2 + 0];
                d1 += p0 * w1s[c * 2 + 1];
            }
        }
        dspL[tid * 2 + 0] = d0;
        dspL[tid * 2 + 1] = d1;
    }
    __syncthreads();

    // phase E: b-spline + bilinear warp, 4 px/thread
    const int hy = by * 32, hx = bx * 32;
#pragma unroll
    for (int k = 0; k < 4; ++k) {
        const int l = k * 256 + tid;
        const int hh = hy + (l >> 5);
        const int ww = hx + (l & 31);

        const float xg = fminf(ww * 0.125f, 63.0f);
        const float yg = fminf(hh * 0.125f, 63.0f);
        const float u = xg * 0.015625f, v = yg * 0.015625f;
        const int lr = (hh >> 3) - by * 4 + 1;    // local dsp row of jj, in [1,4]
        const int lc = (ww >> 3) - bx * 4 + 1;

        const float u2 = u * u, u3 = u2 * u;
        const float v2 = v * v, v3 = v2 * v;
        const float Bu[4] = {-u3 + 3.f * u2 - 3.f * u + 1.f,
                             3.f * u3 - 6.f * u2 + 4.f,
                             -3.f * u3 + 3.f * u2 + 3.f * u + 1.f,
                             u3};
        const float Bv[4] = {-v3 + 3.f * v2 - 3.f * v + 1.f,
                             3.f * v3 - 6.f * v2 + 4.f,
                             -3.f * v3 + 3.f * v2 + 3.f * v + 1.f,
                             v3};

        float s0 = 0.f, s1 = 0.f;
#pragma unroll
        for (int mm = 0; mm < 4; ++mm) {
            const int row = lr + mm - 1;          // in [0,6]
            float r0 = 0.f, r1 = 0.f;
#pragma unroll
            for (int nn = 0; nn < 4; ++nn) {
                const int col = lc + nn - 1;      // in [0,6]
                const float2 d = *reinterpret_cast<const float2*>(&dspL[(row * 7 + col) * 2]);
                r0 += Bv[nn] * d.x;
                r1 += Bv[nn] * d.y;
            }
            s0 += Bu[mm] * r0;                     // B_u pairs with row axis
            s1 += Bu[mm] * r1;
        }
        const float wx = s0 + (float)ww;
        const float wy = s1 + (float)hh;

        const float fxx = floorf(wx), fyy = floorf(wy);
        const float x0 = fminf(fmaxf(fxx, 0.f), 511.f);
        const float x1 = fminf(fmaxf(fxx + 1.f, 0.f), 511.f);
        const float y0 = fminf(fmaxf(fyy, 0.f), 511.f);
        const float y1 = fminf(fmaxf(fyy + 1.f, 0.f), 511.f);
        const int x0i = (int)x0, x1i = (int)x1, y0i = (int)y0, y1i = (int)y1;

        float ov;
        if (x0i == x1i || y0i == y1i) {
            ov = 0.f;   // exact result of the reference's cancelling arithmetic
        } else {
            const size_t bb = (size_t)b * 262144;
            const float Q1 = mv[bb + (size_t)y0i * 512 + x0i];
            const float Q2 = mv[bb + (size_t)y1i * 512 + x0i];
            const float Q3 = mv[bb + (size_t)y0i * 512 + x1i];
            const float Q4 = mv[bb + (size_t)y1i * 512 + x1i];
            const float invdx = 1.f / (x1 - x0 + 1e-5f);
            const float wxr = (x1 - wx) * invdx, wxl = (wx - x0) * invdx;
            const float R1 = wxr * Q1 + wxl * Q3;
            const float R2 = wxr * Q2 + wxl * Q4;
            const float invdy = 1.f / (y1 - y0 + 1e-5f);
            ov = (y1 - wy) * invdy * R1 + (wy - y0) * invdy * R2;
        }

        const size_t pix = (size_t)hh * 512 + ww;
        out[(size_t)b * 262144 + pix] = ov;                          // warped
        out[1048576 + (size_t)(b * 2 + 0) * 262144 + pix] = wx;      // grid x
        out[1048576 + (size_t)(b * 2 + 1) * 262144 + pix] = wy;      // grid y
    }
}

// ---------------------------------------------------------------------------
extern "C" void kernel_launch(void* const* d_in, const int* in_sizes, int n_in,
                              void* d_out, int out_size, void* d_ws, size_t ws_size,
                              hipStream_t stream) {
    (void)in_sizes; (void)n_in; (void)out_size; (void)ws_size;
    const float* fixed  = (const float*)d_in[0];
    const float* moving = (const float*)d_in[1];
    const float* w0  = (const float*)d_in[2];
    const float* w1  = (const float*)d_in[3];
    const float* w2  = (const float*)d_in[4];
    const float* fw0 = (const float*)d_in[5];
    const float* fw1 = (const float*)d_in[6];
    const float* pw0 = (const float*)d_in[7];
    const float* pw1 = (const float*)d_in[8];

    // d_ws layout (peak 7 MiB, proven safe):
    //   wfr bf16 37888 frags @ [0, 74KB)
    //   a1  bf16 [4,128,128,32] @ [1M, 5.2M)
    //   a2  bf16 [4,64,64,32]   @ [6M, 7M)
    char* base = (char*)d_ws;
    bf16* wfr = (bf16*)base;
    bf16* a1  = (bf16*)(base + (1u << 20));
    bf16* a2  = (bf16*)(base + (6u << 20));

    k_repack<<<148, 256, 0, stream>>>(w1, w2, fw0, fw1, w0, wfr);
    k_front<<<dim3(16, 32, 4), 256, 0, stream>>>(fixed, moving,
                                                 wfr + 36864, wfr + 0 * 9216, a1);
    k_conv2<<<dim3(8, 16, 4), 256, 0, stream>>>(a1, wfr + 1 * 9216, a2, 128, 128);
    k_tail<<<dim3(16, 16, 4), 256, 0, stream>>>(a2, wfr + 2 * 9216, wfr + 3 * 9216,
                                                pw0, pw1, moving, (float*)d_out);
}